// Round 10
// baseline (30185.693 us; speedup 1.0000x reference)
//
#include <hip/hip_runtime.h>
#include <stdint.h>

typedef unsigned long long u64t;

__device__ __forceinline__ float sigf(float x) { return 1.f / (1.f + __expf(-x)); }
__device__ __forceinline__ float tanhf_s(float x) {
    float ax = fabsf(x);
    float t = __expf(-2.f * ax);
    float r = (1.f - t) / (1.f + t);
    return copysignf(r, x);
}

// ---------------------------------------------------------------------------
// K1: char LSTM, register-weight version. 512 blocks x 256 thr, 16 words each.
// (unchanged, 4x proven)
// ---------------------------------------------------------------------------
__global__ __launch_bounds__(256, 2) void k_char_lstm(
    const int* __restrict__ chars, const float* __restrict__ char_emb,
    const float* __restrict__ Wih, const float* __restrict__ Whh,
    const float* __restrict__ bih, const float* __restrict__ bhh,
    float* __restrict__ h_char, int words_per_block)
{
    __shared__ float X[768];
    __shared__ float gl[256];
    __shared__ float hl[64];
    const int t = threadIdx.x;
    const int g = t >> 6, e = t & 63;

    float wih[64], whh[64];
    {
        const float4* p1 = (const float4*)(Wih + t * 64);
        const float4* p2 = (const float4*)(Whh + t * 64);
#pragma unroll
        for (int q = 0; q < 16; ++q) {
            float4 a = p1[q];
            wih[4*q+0] = a.x; wih[4*q+1] = a.y; wih[4*q+2] = a.z; wih[4*q+3] = a.w;
        }
#pragma unroll
        for (int q = 0; q < 16; ++q) {
            float4 b = p2[q];
            whh[4*q+0] = b.x; whh[4*q+1] = b.y; whh[4*q+2] = b.z; whh[4*q+3] = b.w;
        }
    }
    const float bias = bih[t] + bhh[t];

    for (int wi = 0; wi < words_per_block; ++wi) {
        const int w = blockIdx.x * words_per_block + wi;
        const int* crow = chars + w * 12;
        for (int q = t; q < 768; q += 256)
            X[q] = char_emb[crow[q >> 6] * 64 + (q & 63)];
        if (t < 64) hl[t] = 0.f;
        __syncthreads();

        float c = 0.f, hreg = 0.f;
        for (int st = 0; st < 12; ++st) {
            float s_ = bias;
            const float4* xv4 = (const float4*)(X + st * 64);
            const float4* hv4 = (const float4*)hl;
#pragma unroll
            for (int q = 0; q < 16; ++q) {
                float4 x4 = xv4[q];
                s_ += wih[4*q+0]*x4.x + wih[4*q+1]*x4.y + wih[4*q+2]*x4.z + wih[4*q+3]*x4.w;
            }
#pragma unroll
            for (int q = 0; q < 16; ++q) {
                float4 h4 = hv4[q];
                s_ += whh[4*q+0]*h4.x + whh[4*q+1]*h4.y + whh[4*q+2]*h4.z + whh[4*q+3]*h4.w;
            }
            gl[t] = (g == 2) ? tanhf_s(s_) : sigf(s_);
            __syncthreads();
            if (g == 0) {
                float ii = gl[e], ff = gl[64 + e], gg = gl[128 + e], oo = gl[192 + e];
                c = ff * c + ii * gg;
                hreg = oo * tanhf_s(c);
                hl[e] = hreg;
            }
            __syncthreads();
        }
        if (g == 0) h_char[w * 64 + e] = hreg;
    }
}

// ---------------------------------------------------------------------------
// K2: X[w] = [word_emb[sent[w]] (256) | h_char[w] (64)]. f32.
// ---------------------------------------------------------------------------
__global__ __launch_bounds__(320) void k_build_x(
    const int* __restrict__ sentence, const float* __restrict__ word_emb,
    const float* __restrict__ h_char, float* __restrict__ X)
{
    const int w = blockIdx.x, t = threadIdx.x;
    float v;
    if (t < 256) v = word_emb[(size_t)sentence[w] * 256 + t];
    else         v = h_char[(size_t)w * 64 + (t - 256)];
    X[(size_t)w * 320 + t] = v;
}

// ---------------------------------------------------------------------------
// K3: pack W_out [64][512] -> WP[k4*256 + j*4 + c] = W_out[j][k4*4+c]
// ---------------------------------------------------------------------------
__global__ __launch_bounds__(256) void k_pack_wout(const float* __restrict__ W_out, float* __restrict__ WP)
{
    int i = blockIdx.x * 256 + threadIdx.x;
    int c = i & 3, j = (i >> 2) & 63, k4 = i >> 8;
    WP[i] = W_out[j * 512 + k4 * 4 + c];
}

// ---------------------------------------------------------------------------
// K4: persistent word LSTM, f32, LDS-RESIDENT WEIGHTS (allocator-proof).
// 128 WGs x 512 thr; WG wg owns h elems E = wg*4 + e (e=0..3) = 16 gate rows.
// Thread map: e=t>>7, g=(t>>5)&3, ks=t&31 (k-slice of 16), w=t>>6, lane=t&63.
// LDS: W2 (Whh, 32KB) and XI (Wih, 20KB) in LANE-INTERLEAVED layout:
//   W2[((w*4+c)*64+lane)*4 + j]  = Whh[grow][ks*16 + c*4 + j]   (c=0..3)
//   XI[((w*5+c)*64+lane)*2 + j]  = Wih[grow][ks*10 + c*2 + j]   (c=0..4)
// so per-wave hot-loop ds_reads are contiguous 16B/lane = conflict-free, and
// each thread reads back exactly what it wrote (layout-proof correctness).
// Total static LDS ~55.6KB < 64KB (no dynamic-LDS attribute needed).
// Per step: xdot (X global + XI, independent of h, overlaps producers) ->
// poll own slot (r6-proven agent-scope tagged u64, double-buffered
// Hpub[2][512], slot parity s&1 = tag s) -> stage h2 -> barrier1(+abort) ->
// hdot (4x ds_read_b128 W2 + 4x b128 h2, 16 MAC) -> 32-lane shfl reduce ->
// act (1 exp) -> gl[e][g] via LDS -> barrier2 -> cell update (redundant
// across elem group) -> publisher (t%128==0) stores tag s+1 + ys.
// Race-freedom: stage(s+1) only after poll sees tag s+1, published after
// barrier2(s), which all hdot(s) reads precede. gl(s+1) written after
// barrier1(s+1), which all gl(s) reads precede. No overtaking: tag s+2 into
// a buffer requires all WGs consumed tag s (barrier1 orders polls first).
// Abort: global poll budget, uniform via __syncthreads_or -> never hangs.
// ---------------------------------------------------------------------------
#define PLOAD(p) __hip_atomic_load((p), __ATOMIC_RELAXED, __HIP_MEMORY_SCOPE_AGENT)

__global__ __launch_bounds__(512, 1) void k_word_lstm(
    const float* __restrict__ Whh, const float* __restrict__ Wih,
    const float* __restrict__ X,
    const float* __restrict__ bih, const float* __restrict__ bhh,
    u64t* Hpub, float* __restrict__ ys)
{
    __shared__ float W2[8192];     // 32 KB
    __shared__ float XI[5120];     // 20 KB
    __shared__ float h2[576];      // h[k] at (k>>4)*18 + (k&15)
    __shared__ float gl[16];       // [e][g]
    const int t = threadIdx.x, wg = blockIdx.x;
    const int e = t >> 7, g = (t >> 5) & 3, ks = t & 31;
    const int w = t >> 6, lane = t & 63;
    const int grow = g * 512 + wg * 4 + e;
    const int E = wg * 4 + e;

    // ---- one-time: fill interleaved weight LDS (each thread its own slice)
    {
        const float4* src = (const float4*)(Whh + (size_t)grow * 512 + ks * 16);
#pragma unroll
        for (int c = 0; c < 4; ++c) {
            float4 v = src[c];
            *(float4*)&W2[(((w * 4 + c) * 64) + lane) * 4] = v;
        }
        const float2* s2 = (const float2*)(Wih + (size_t)grow * 320 + ks * 10);
#pragma unroll
        for (int c = 0; c < 5; ++c) {
            float2 v = s2[c];
            *(float2*)&XI[(((w * 5 + c) * 64) + lane) * 2] = v;
        }
    }
    const float bias = bih[grow] + bhh[grow];
    __syncthreads();

    const bool glw = ((t & 31) == 0);   // gate writer (ks==0)
    const bool pub = ((t & 127) == 0);  // publisher (g==0, ks==0)
    float c = 0.f;
    int bud = 1 << 20;

    for (int s = 0; s < 8192; ++s) {
        // ---- xdot: independent of h_{s-1}
        float xa = 0.f;
        {
            const float2* xr = (const float2*)(X + (size_t)s * 320 + ks * 10);
#pragma unroll
            for (int cc = 0; cc < 5; ++cc) {
                float2 wv = *(const float2*)&XI[(((w * 5 + cc) * 64) + lane) * 2];
                float2 xv = xr[cc];
                xa += wv.x * xv.x + wv.y * xv.y;
            }
        }

        // ---- poll own slot (1 relaxed agent load in flight)
        const unsigned want = (unsigned)s;
        const u64t* sl = Hpub + ((s & 1) << 9) + t;
        u64t v;
        do { v = PLOAD(sl); } while ((unsigned)(v >> 32) != want && --bud > 0);
        h2[((t >> 4) * 18) + (t & 15)] = __uint_as_float((unsigned)v);

        if (__syncthreads_or(bud <= 0)) break;   // barrier1 + uniform abort

        // ---- hdot over h[ks*16 .. +16)
        float s0 = 0.f, s1 = 0.f, s2_ = 0.f, s3 = 0.f;
#pragma unroll
        for (int cc = 0; cc < 4; ++cc) {
            float4 wv = *(const float4*)&W2[(((w * 4 + cc) * 64) + lane) * 4];
            float4 hv = *(const float4*)&h2[ks * 18 + cc * 4];
            s0 += wv.x * hv.x;
            s1 += wv.y * hv.y;
            s2_ += wv.z * hv.z;
            s3 += wv.w * hv.w;
        }
        float sum = ((s0 + s1) + (s2_ + s3)) + xa;
        sum += __shfl_xor(sum, 1);
        sum += __shfl_xor(sum, 2);
        sum += __shfl_xor(sum, 4);
        sum += __shfl_xor(sum, 8);
        sum += __shfl_xor(sum, 16);
        sum += bias;                  // row sum (uniform across 32 ks lanes)

        // activation: tanh for g==2, sigmoid else (one exp)
        float y  = (g == 2) ? sum : 0.5f * sum;
        float ax = fabsf(y);
        float ez = __expf(-2.f * ax);
        float th = copysignf((1.f - ez) / (1.f + ez), y);
        float act = (g == 2) ? th : 0.5f * th + 0.5f;

        if (glw) gl[e * 4 + g] = act;
        __syncthreads();              // barrier2: gates visible

        float ii = gl[e * 4 + 0], ff = gl[e * 4 + 1];
        float gg = gl[e * 4 + 2], oo = gl[e * 4 + 3];
        c = ff * c + ii * gg;         // identical across elem group
        float h = oo * tanhf_s(c);

        if (pub) {
            u64t pv = ((u64t)(s + 1) << 32) | (u64t)__float_as_uint(h);
            __hip_atomic_store(Hpub + (((s + 1) & 1) << 9) + E, pv,
                               __ATOMIC_RELAXED, __HIP_MEMORY_SCOPE_AGENT);
            ys[(size_t)s * 512 + E] = h;
        }
    }
}
#undef PLOAD

// ---------------------------------------------------------------------------
// K5: logits = ys @ W_out.T + b_out, log_softmax per row. 4 rows/block.
// ---------------------------------------------------------------------------
__global__ __launch_bounds__(256) void k_proj(
    const float* __restrict__ ys, const float* __restrict__ WP,
    const float* __restrict__ b_out, float* __restrict__ out)
{
    __shared__ float yl[4 * 516];
    const int t = threadIdx.x;
    const size_t base = (size_t)blockIdx.x * 4 * 512;
#pragma unroll
    for (int i = 0; i < 8; ++i) {
        int q = t + 256 * i;
        yl[(q >> 9) * 516 + (q & 511)] = ys[base + q];
    }
    __syncthreads();
    const int row = t >> 6, j = t & 63;
    const float* yr = yl + row * 516;
    float acc = b_out[j];
    for (int k4 = 0; k4 < 128; ++k4) {
        float4 wv = *(const float4*)(WP + k4 * 256 + j * 4);
        float4 yv = *(const float4*)(yr + k4 * 4);
        acc += wv.x * yv.x + wv.y * yv.y + wv.z * yv.z + wv.w * yv.w;
    }
    float m = acc;
#pragma unroll
    for (int d = 1; d < 64; d <<= 1) m = fmaxf(m, __shfl_xor(m, d));
    float p = __expf(acc - m);
    float ssum = p;
#pragma unroll
    for (int d = 1; d < 64; d <<= 1) ssum += __shfl_xor(ssum, d);
    out[(size_t)blockIdx.x * 256 + t] = acc - m - __logf(ssum);
}

__global__ void k_signal(float* out, float v) { out[0] = v; }

// ---------------------------------------------------------------------------
extern "C" void kernel_launch(void* const* d_in, const int* in_sizes, int n_in,
                              void* d_out, int out_size, void* d_ws, size_t ws_size,
                              hipStream_t stream)
{
    const int*   char_sentence = (const int*)d_in[0];
    const int*   sentence      = (const int*)d_in[1];
    const float* char_emb      = (const float*)d_in[2];
    const float* word_emb      = (const float*)d_in[3];
    const float* Wih_c         = (const float*)d_in[4];
    const float* Whh_c         = (const float*)d_in[5];
    const float* bih_c         = (const float*)d_in[6];
    const float* bhh_c         = (const float*)d_in[7];
    const float* Wih_w         = (const float*)d_in[8];
    const float* Whh_w         = (const float*)d_in[9];
    const float* bih_w         = (const float*)d_in[10];
    const float* bhh_w         = (const float*)d_in[11];
    const float* W_out         = (const float*)d_in[12];
    const float* b_out         = (const float*)d_in[13];
    float* out = (float*)d_out;
    char* ws = (char*)d_ws;

    // ws layout (all f32)
    float* X      = (float*)(ws);                        // 8192*320*4 = 10,485,760
    float* ys     = (float*)(ws + 10485760);             // 8192*512*4 = 16,777,216
    float* h_char = (float*)(ws + 27262976);             // 8192*64*4  =  2,097,152
    u64t*  Hpub   = (u64t*)(ws + 29360128);              // 2*512*8    =      8,192
    float* WP     = (float*)(ws + 29368320);             // 64*512*4   =    131,072
    const size_t need = 29368320 + 131072;
    if (ws_size < need) {
        k_signal<<<1, 1, 0, stream>>>(out, (float)(ws_size >> 20));
        return;
    }

    k_char_lstm<<<512, 256, 0, stream>>>(char_sentence, char_emb, Wih_c, Whh_c, bih_c, bhh_c, h_char, 16);
    k_build_x<<<8192, 320, 0, stream>>>(sentence, word_emb, h_char, X);
    k_pack_wout<<<128, 256, 0, stream>>>(W_out, WP);
    hipMemsetAsync(Hpub, 0, 8192, stream);  // reset both tag buffers every launch
    k_word_lstm<<<128, 512, 0, stream>>>(Whh_w, Wih_w, X, bih_w, bhh_w, Hpub, ys);
    k_proj<<<2048, 256, 0, stream>>>(ys, WP, b_out, out);
}

// Round 11
// 17255.887 us; speedup vs baseline: 1.7493x; 1.7493x over previous
//
#include <hip/hip_runtime.h>
#include <stdint.h>

typedef unsigned long long u64t;

__device__ __forceinline__ float sigf(float x) { return 1.f / (1.f + __expf(-x)); }
__device__ __forceinline__ float tanhf_s(float x) {
    float ax = fabsf(x);
    float t = __expf(-2.f * ax);
    float r = (1.f - t) / (1.f + t);
    return copysignf(r, x);
}

// ---------------------------------------------------------------------------
// K1: char LSTM, register-weight version. 512 blocks x 256 thr, 16 words each.
// ---------------------------------------------------------------------------
__global__ __launch_bounds__(256, 2) void k_char_lstm(
    const int* __restrict__ chars, const float* __restrict__ char_emb,
    const float* __restrict__ Wih, const float* __restrict__ Whh,
    const float* __restrict__ bih, const float* __restrict__ bhh,
    float* __restrict__ h_char, int words_per_block)
{
    __shared__ float X[768];
    __shared__ float gl[256];
    __shared__ float hl[64];
    const int t = threadIdx.x;
    const int g = t >> 6, e = t & 63;

    float wih[64], whh[64];
    {
        const float4* p1 = (const float4*)(Wih + t * 64);
        const float4* p2 = (const float4*)(Whh + t * 64);
#pragma unroll
        for (int q = 0; q < 16; ++q) {
            float4 a = p1[q];
            wih[4*q+0] = a.x; wih[4*q+1] = a.y; wih[4*q+2] = a.z; wih[4*q+3] = a.w;
        }
#pragma unroll
        for (int q = 0; q < 16; ++q) {
            float4 b = p2[q];
            whh[4*q+0] = b.x; whh[4*q+1] = b.y; whh[4*q+2] = b.z; whh[4*q+3] = b.w;
        }
    }
    const float bias = bih[t] + bhh[t];

    for (int wi = 0; wi < words_per_block; ++wi) {
        const int w = blockIdx.x * words_per_block + wi;
        const int* crow = chars + w * 12;
        for (int q = t; q < 768; q += 256)
            X[q] = char_emb[crow[q >> 6] * 64 + (q & 63)];
        if (t < 64) hl[t] = 0.f;
        __syncthreads();

        float c = 0.f, hreg = 0.f;
        for (int st = 0; st < 12; ++st) {
            float s_ = bias;
            const float4* xv4 = (const float4*)(X + st * 64);
            const float4* hv4 = (const float4*)hl;
#pragma unroll
            for (int q = 0; q < 16; ++q) {
                float4 x4 = xv4[q];
                s_ += wih[4*q+0]*x4.x + wih[4*q+1]*x4.y + wih[4*q+2]*x4.z + wih[4*q+3]*x4.w;
            }
#pragma unroll
            for (int q = 0; q < 16; ++q) {
                float4 h4 = hv4[q];
                s_ += whh[4*q+0]*h4.x + whh[4*q+1]*h4.y + whh[4*q+2]*h4.z + whh[4*q+3]*h4.w;
            }
            gl[t] = (g == 2) ? tanhf_s(s_) : sigf(s_);
            __syncthreads();
            if (g == 0) {
                float ii = gl[e], ff = gl[64 + e], gg = gl[128 + e], oo = gl[192 + e];
                c = ff * c + ii * gg;
                hreg = oo * tanhf_s(c);
                hl[e] = hreg;
            }
            __syncthreads();
        }
        if (g == 0) h_char[w * 64 + e] = hreg;
    }
}

// ---------------------------------------------------------------------------
// K2: X[w] = [word_emb[sent[w]] (256) | h_char[w] (64)]. f32.
// ---------------------------------------------------------------------------
__global__ __launch_bounds__(320) void k_build_x(
    const int* __restrict__ sentence, const float* __restrict__ word_emb,
    const float* __restrict__ h_char, float* __restrict__ X)
{
    const int w = blockIdx.x, t = threadIdx.x;
    float v;
    if (t < 256) v = word_emb[(size_t)sentence[w] * 256 + t];
    else         v = h_char[(size_t)w * 64 + (t - 256)];
    X[(size_t)w * 320 + t] = v;
}

// ---------------------------------------------------------------------------
// K3: pack W_out [64][512] -> WP[k4*256 + j*4 + c] = W_out[j][k4*4+c]
// ---------------------------------------------------------------------------
__global__ __launch_bounds__(256) void k_pack_wout(const float* __restrict__ W_out, float* __restrict__ WP)
{
    int i = blockIdx.x * 256 + threadIdx.x;
    int c = i & 3, j = (i >> 2) & 63, k4 = i >> 8;
    WP[i] = W_out[j * 512 + k4 * 4 + c];
}

// ---------------------------------------------------------------------------
// K4: persistent word LSTM, f32, LDS weights + LINE-PADDED tag slots.
// 128 WGs x 256 thr; WG owns elems E = wg*4 + e. Map: e=t>>6 (wave), g=(t>>4)&3,
// ks=t&15. Per-thread: Whh slice 32f + Wih slice 20f in lane-interleaved LDS
// (reads back its own writes -> layout-proof; contiguous 16B/lane, conflict-
// free). 54KB static LDS. All 4 gates of an elem live in ONE wave -> shfl
// butterfly (r6-proven), no gate LDS, ONE barrier per step.
// Exchange: Hpub[2][512][8] u64 — each tagged slot PADDED TO ITS OWN 64B LINE
// (spinners/line: 512 -> 128; r6/r10 evidence says same-line poll contention
// sets the step floor). Slot parity s&1 holds tag s (tag<<32 | f32 bits).
// h2 staging DOUBLE-BUFFERED by s&1: closes r6's stale-by-one overwrite race
// without a second barrier. Proof: wave stages h2[p] at step s+2 only after
// seeing remote tag s+2 => that WG passed barrier1(s+1) => polls saw ALL tags
// s+1 incl. ours => every wave here (each has publisher lane0) passed
// hdot(s) reads of h2[p]. No-overtake of Hpub buffers: as r3-r10.
// Abort: global poll budget + __syncthreads_or -> bounded, never hangs.
// ---------------------------------------------------------------------------
#define PLOAD(p) __hip_atomic_load((p), __ATOMIC_RELAXED, __HIP_MEMORY_SCOPE_AGENT)

__global__ __launch_bounds__(256, 1) void k_word_lstm(
    const float* __restrict__ Whh, const float* __restrict__ Wih,
    const float* __restrict__ X,
    const float* __restrict__ bih, const float* __restrict__ bhh,
    u64t* Hpub, float* __restrict__ ys)
{
    __shared__ float W2[4][8][64][4];   // 32 KB: [wave][cc][lane][j]
    __shared__ float XI[4][5][64][4];   // 20 KB
    __shared__ float h2[2][576];        // double-buffered, stride-36 padded
    const int t = threadIdx.x, wg = blockIdx.x;
    const int e = t >> 6, g = (t >> 4) & 3, ks = t & 15;
    const int lane = t & 63;
    const int E = wg * 4 + e;
    const int grow = g * 512 + E;

    // one-time LDS fill: each thread writes exactly what it will read back
    {
        const float4* src = (const float4*)(Whh + (size_t)grow * 512 + ks * 32);
#pragma unroll
        for (int cc = 0; cc < 8; ++cc)
            *(float4*)&W2[e][cc][lane][0] = src[cc];
        const float4* s2 = (const float4*)(Wih + (size_t)grow * 320 + ks * 20);
#pragma unroll
        for (int cc = 0; cc < 5; ++cc)
            *(float4*)&XI[e][cc][lane][0] = s2[cc];
    }
    const float bias = bih[grow] + bhh[grow];
    __syncthreads();

    const bool pub = ((t & 63) == 0);        // lane0 of each wave
    const int pidx1 = ((t >> 5) * 36) + (t & 31);          // stage elem t
    const int pidx2 = ((8 + (t >> 5)) * 36) + (t & 31);    // stage elem t+256
    float c = 0.f;
    int bud = 1 << 20;

    for (int s = 0; s < 8192; ++s) {
        // ---- xdot: independent of h_{s-1}; overlaps producers' publish
        float xa = 0.f;
        {
            const float4* xr = (const float4*)(X + (size_t)s * 320 + ks * 20);
#pragma unroll
            for (int cc = 0; cc < 5; ++cc) {
                float4 wv = *(const float4*)&XI[e][cc][lane][0];
                float4 xv = xr[cc];
                xa += wv.x * xv.x + wv.y * xv.y + wv.z * xv.z + wv.w * xv.w;
            }
        }

        // ---- poll 2 line-padded slots (elems t and t+256), both in flight
        const unsigned want = (unsigned)s;
        const u64t* base = Hpub + ((size_t)(s & 1) << 12);
        const u64t* sl1 = base + (size_t)t * 8;
        const u64t* sl2 = base + (size_t)(t + 256) * 8;
        u64t v1, v2;
        bool d1 = false, d2 = false;
        do {
            if (!d1) { v1 = PLOAD(sl1); d1 = ((unsigned)(v1 >> 32) == want); }
            if (!d2) { v2 = PLOAD(sl2); d2 = ((unsigned)(v2 >> 32) == want); }
        } while (!(d1 && d2) && --bud > 0);
        float* hbuf = h2[s & 1];
        hbuf[pidx1] = __uint_as_float((unsigned)v1);
        hbuf[pidx2] = __uint_as_float((unsigned)v2);

        if (__syncthreads_or(bud <= 0)) break;   // barrier1 + uniform abort

        // ---- hdot over h[ks*32 .. +32)
        float s0 = 0.f, s1 = 0.f, s2_ = 0.f, s3 = 0.f;
        const float* hb = hbuf + ks * 36;
#pragma unroll
        for (int cc = 0; cc < 8; ++cc) {
            float4 wv = *(const float4*)&W2[e][cc][lane][0];
            float4 hv = *(const float4*)(hb + cc * 4);
            s0 += wv.x * hv.x;
            s1 += wv.y * hv.y;
            s2_ += wv.z * hv.z;
            s3 += wv.w * hv.w;
        }
        float sum = ((s0 + s1) + (s2_ + s3)) + xa;
        sum += __shfl_xor(sum, 1);
        sum += __shfl_xor(sum, 2);
        sum += __shfl_xor(sum, 4);
        sum += __shfl_xor(sum, 8);
        sum += bias;                  // row sum, uniform across 16 ks lanes

        // activation: tanh for g==2, sigmoid else (one exp)
        float y  = (g == 2) ? sum : 0.5f * sum;
        float ax = fabsf(y);
        float ez = __expf(-2.f * ax);
        float th = copysignf((1.f - ez) / (1.f + ez), y);
        float act = (g == 2) ? th : 0.5f * th + 0.5f;

        // gate butterfly (g at lane bits 4,5) — r6-proven
        float b16 = __shfl_xor(act, 16);
        float b32 = __shfl_xor(act, 32);
        float b48 = __shfl_xor(b16, 32);
        float ii = (g == 0) ? act : (g == 1) ? b16 : (g == 2) ? b32 : b48;
        float ff = (g == 0) ? b16 : (g == 1) ? act : (g == 2) ? b48 : b32;
        float gg = (g == 0) ? b32 : (g == 1) ? b48 : (g == 2) ? act : b16;
        float oo = (g == 0) ? b48 : (g == 1) ? b32 : (g == 2) ? b16 : act;

        c = ff * c + ii * gg;         // identical across the wave (elem e)
        float h = oo * tanhf_s(c);

        if (pub) {
            u64t pv = ((u64t)(s + 1) << 32) | (u64t)__float_as_uint(h);
            __hip_atomic_store(Hpub + ((size_t)((s + 1) & 1) << 12) + (size_t)E * 8, pv,
                               __ATOMIC_RELAXED, __HIP_MEMORY_SCOPE_AGENT);
            ys[(size_t)s * 512 + E] = h;
        }
    }
}
#undef PLOAD

// ---------------------------------------------------------------------------
// K5: logits = ys @ W_out.T + b_out, log_softmax per row. 4 rows/block.
// ---------------------------------------------------------------------------
__global__ __launch_bounds__(256) void k_proj(
    const float* __restrict__ ys, const float* __restrict__ WP,
    const float* __restrict__ b_out, float* __restrict__ out)
{
    __shared__ float yl[4 * 516];
    const int t = threadIdx.x;
    const size_t base = (size_t)blockIdx.x * 4 * 512;
#pragma unroll
    for (int i = 0; i < 8; ++i) {
        int q = t + 256 * i;
        yl[(q >> 9) * 516 + (q & 511)] = ys[base + q];
    }
    __syncthreads();
    const int row = t >> 6, j = t & 63;
    const float* yr = yl + row * 516;
    float acc = b_out[j];
    for (int k4 = 0; k4 < 128; ++k4) {
        float4 wv = *(const float4*)(WP + k4 * 256 + j * 4);
        float4 yv = *(const float4*)(yr + k4 * 4);
        acc += wv.x * yv.x + wv.y * yv.y + wv.z * yv.z + wv.w * yv.w;
    }
    float m = acc;
#pragma unroll
    for (int d = 1; d < 64; d <<= 1) m = fmaxf(m, __shfl_xor(m, d));
    float p = __expf(acc - m);
    float ssum = p;
#pragma unroll
    for (int d = 1; d < 64; d <<= 1) ssum += __shfl_xor(ssum, d);
    out[(size_t)blockIdx.x * 256 + t] = acc - m - __logf(ssum);
}

__global__ void k_signal(float* out, float v) { out[0] = v; }

// ---------------------------------------------------------------------------
extern "C" void kernel_launch(void* const* d_in, const int* in_sizes, int n_in,
                              void* d_out, int out_size, void* d_ws, size_t ws_size,
                              hipStream_t stream)
{
    const int*   char_sentence = (const int*)d_in[0];
    const int*   sentence      = (const int*)d_in[1];
    const float* char_emb      = (const float*)d_in[2];
    const float* word_emb      = (const float*)d_in[3];
    const float* Wih_c         = (const float*)d_in[4];
    const float* Whh_c         = (const float*)d_in[5];
    const float* bih_c         = (const float*)d_in[6];
    const float* bhh_c         = (const float*)d_in[7];
    const float* Wih_w         = (const float*)d_in[8];
    const float* Whh_w         = (const float*)d_in[9];
    const float* bih_w         = (const float*)d_in[10];
    const float* bhh_w         = (const float*)d_in[11];
    const float* W_out         = (const float*)d_in[12];
    const float* b_out         = (const float*)d_in[13];
    float* out = (float*)d_out;
    char* ws = (char*)d_ws;

    // ws layout (all f32)
    float* X      = (float*)(ws);                        // 8192*320*4 = 10,485,760
    float* ys     = (float*)(ws + 10485760);             // 8192*512*4 = 16,777,216
    float* h_char = (float*)(ws + 27262976);             // 8192*64*4  =  2,097,152
    u64t*  Hpub   = (u64t*)(ws + 29360128);              // 2*512*64   =     65,536
    float* WP     = (float*)(ws + 29425664);             // 64*512*4   =    131,072
    const size_t need = 29425664 + 131072;
    if (ws_size < need) {
        k_signal<<<1, 1, 0, stream>>>(out, (float)(ws_size >> 20));
        return;
    }

    k_char_lstm<<<512, 256, 0, stream>>>(char_sentence, char_emb, Wih_c, Whh_c, bih_c, bhh_c, h_char, 16);
    k_build_x<<<8192, 320, 0, stream>>>(sentence, word_emb, h_char, X);
    k_pack_wout<<<128, 256, 0, stream>>>(W_out, WP);
    hipMemsetAsync(Hpub, 0, 65536, stream);  // reset both line-padded tag buffers
    k_word_lstm<<<128, 256, 0, stream>>>(Whh_w, Wih_w, X, bih_w, bhh_w, Hpub, ys);
    k_proj<<<2048, 256, 0, stream>>>(ys, WP, b_out, out);
}